// Round 2
// baseline (565.815 us; speedup 1.0000x reference)
//
#include <hip/hip_runtime.h>

#define B_ 4
#define S_ 2048
#define D_ 1024
#define H_ 16
#define KD_ 64
#define P_ 1024
#define M_ (B_*S_)

typedef unsigned short u16;
typedef unsigned int u32;
typedef __attribute__((ext_vector_type(2))) unsigned u32x2;
typedef __attribute__((ext_vector_type(4))) float f32x4;
typedef __attribute__((ext_vector_type(8))) __bf16 bf16x8;

__device__ __forceinline__ u16 f2bf(float f) {
  u32 x = __float_as_uint(f);
  return (u16)((x + 0x7fffu + ((x >> 16) & 1u)) >> 16);
}

__device__ __forceinline__ void gl_lds16(const u16* g, u16* l) {
  __builtin_amdgcn_global_load_lds((__attribute__((address_space(1))) void*)g,
                                   (__attribute__((address_space(3))) void*)l, 16, 0, 0);
}

// pack bf16(b)<<16 | bf16(a), round-to-nearest (+0x8000 then take hi16 via v_perm)
__device__ __forceinline__ u32 pkbf(float a, float b) {
  return __builtin_amdgcn_perm(__float_as_uint(b) + 0x8000u,
                               __float_as_uint(a) + 0x8000u, 0x07060302u);
}

// Quad redistribution for P -> PV B-operand (see attn_kernel comment).
// After this: a = [a@q0, a@q2, b@q0, b@q2], b = [a@q1, a@q3, b@q1, b@q3]
// (x@qN = value of x at source quad N, same l16).
#if __has_builtin(__builtin_amdgcn_permlane32_swap) && __has_builtin(__builtin_amdgcn_permlane16_swap)
__device__ __forceinline__ void plswap(u32& a, u32& b) {
  u32x2 r32 = __builtin_amdgcn_permlane32_swap(a, b, false, false);
  u32x2 r16 = __builtin_amdgcn_permlane16_swap(r32[0], r32[1], false, false);
  a = r16[0]; b = r16[1];
}
#else
__device__ __forceinline__ void plswap(u32& a, u32& b) {
  const int l = threadIdx.x & 63;
  const int quad = l >> 4, l16 = l & 15;
  // dest quad d: a' <- src quad 2*(d&1) of (d<2 ? a : b); b' <- src quad 2*(d&1)+1
  int i0 = (((quad & 1) * 32) + l16) * 4;        // src lane 2*(d&1)*16 + l16
  int i1 = i0 + 64;                               // +16 lanes
  int a_lo = __builtin_amdgcn_ds_bpermute(i0, (int)a);
  int b_lo = __builtin_amdgcn_ds_bpermute(i0, (int)b);
  int a_hi = __builtin_amdgcn_ds_bpermute(i1, (int)a);
  int b_hi = __builtin_amdgcn_ds_bpermute(i1, (int)b);
  u32 na = (quad < 2) ? (u32)a_lo : (u32)b_lo;
  u32 nb = (quad < 2) ? (u32)a_hi : (u32)b_hi;
  a = na; b = nb;
}
#endif

// ---------------- fp32 -> bf16 convert, 3 tensors in one launch ----------------
__global__ void cvt3_kernel(const float* __restrict__ q, const float* __restrict__ k,
                            const float* __restrict__ v,
                            u16* __restrict__ Xq, u16* __restrict__ Xk, u16* __restrict__ Xv) {
  const int z = blockIdx.y;
  const float* in = z == 0 ? q : z == 1 ? k : v;
  u16* out = z == 0 ? Xq : z == 1 ? Xk : Xv;
  int i = blockIdx.x * 256 + threadIdx.x;
  float4 vv = ((const float4*)in)[i];
  ((u32*)out)[i*2+0] = (u32)f2bf(vv.x) | ((u32)f2bf(vv.y) << 16);
  ((u32*)out)[i*2+1] = (u32)f2bf(vv.z) | ((u32)f2bf(vv.w) << 16);
}

// ---------------- transpose 1024x1024 fp32 -> bf16 [C][R], 4 weights ----------------
__global__ void transpose_cvt4(const float* __restrict__ Wq, const float* __restrict__ Wk,
                               const float* __restrict__ Wv, const float* __restrict__ Wo,
                               u16* __restrict__ WqT, u16* __restrict__ WkT,
                               u16* __restrict__ WvT, u16* __restrict__ WoT) {
  const int z = blockIdx.z;
  const float* in = z == 0 ? Wq : z == 1 ? Wk : z == 2 ? Wv : Wo;
  u16* out = z == 0 ? WqT : z == 1 ? WkT : z == 2 ? WvT : WoT;
  __shared__ float tile[32][33];
  int bx = blockIdx.x * 32, by = blockIdx.y * 32;
  int tx = threadIdx.x, ty = threadIdx.y; // block (32,8)
  #pragma unroll
  for (int kk = 0; kk < 4; ++kk)
    tile[ty + kk*8][tx] = in[(by + ty + kk*8) * 1024 + bx + tx];
  __syncthreads();
  #pragma unroll
  for (int kk = 0; kk < 4; ++kk)
    out[(bx + ty + kk*8) * 1024 + by + tx] = f2bf(tile[tx][ty + kk*8]);
}

// ---------------- QKV projection GEMM (batched, z selects), m97 pattern ----------------
// z=0: Q -> Qb [row][P]; z=1: K -> Kb [row][P]; z=2: V -> Vt [b][h][d][s] (transposed!)
__global__ __launch_bounds__(256) void gemm_qkv(
    const u16* __restrict__ Xq, const u16* __restrict__ Xk, const u16* __restrict__ Xv,
    const u16* __restrict__ WqT, const u16* __restrict__ WkT, const u16* __restrict__ WvT,
    const float* __restrict__ bq, const float* __restrict__ bk, const float* __restrict__ bv,
    u16* __restrict__ Qb, u16* __restrict__ Kb, u16* __restrict__ Vt)
{
  constexpr int K = 1024, N = 1024, BK = 32;
  const int z = blockIdx.z;
  const u16* A  = z == 0 ? Xq  : z == 1 ? Xk  : Xv;
  const u16* Bt = z == 0 ? WqT : z == 1 ? WkT : WvT;
  const float* bias = z == 0 ? bq : z == 1 ? bk : bv;

  __shared__ alignas(16) u16 As[128*BK];
  __shared__ alignas(16) u16 Bs[128*BK];
  const int tid = threadIdx.x;
  const int w = tid >> 6, l = tid & 63;
  const int quad = l >> 4, l16 = l & 15;
  const int wm = (w >> 1) * 64, wn = (w & 1) * 64;
  const long mBase = (long)blockIdx.x * 128;
  const int  nBase = blockIdx.y * 128;

  f32x4 acc[4][4] = {};
  const int off0 = w*1024 + l*16;

  for (int kb = 0; kb < K/BK; ++kb) {
    __syncthreads();
    #pragma unroll
    for (int p = 0; p < 2; ++p) {
      int off = p*4096 + off0;
      int row = off >> 6;
      int cb  = off & 63;
      const u16* ga = A  + (mBase + row)*K + kb*BK + (cb >> 1);
      const u16* gb = Bt + ((long)(nBase + row))*K + kb*BK + (cb >> 1);
      gl_lds16(ga, (u16*)((char*)As + p*4096 + w*1024));
      gl_lds16(gb, (u16*)((char*)Bs + p*4096 + w*1024));
    }
    __syncthreads();
    bf16x8 af[4], bf[4];
    #pragma unroll
    for (int i = 0; i < 4; ++i) af[i] = *(const bf16x8*)&As[(wm + i*16 + l16)*BK + quad*8];
    #pragma unroll
    for (int j = 0; j < 4; ++j) bf[j] = *(const bf16x8*)&Bs[(wn + j*16 + l16)*BK + quad*8];
    #pragma unroll
    for (int i = 0; i < 4; ++i)
      #pragma unroll
      for (int j = 0; j < 4; ++j)
        acc[i][j] = __builtin_amdgcn_mfma_f32_16x16x32_bf16(af[i], bf[j], acc[i][j], 0, 0, 0);
  }

  if (z < 2) {
    u16* Cout = z == 0 ? Qb : Kb;
    #pragma unroll
    for (int i = 0; i < 4; ++i)
      #pragma unroll
      for (int j = 0; j < 4; ++j)
        #pragma unroll
        for (int r = 0; r < 4; ++r) {
          long row = mBase + wm + i*16 + quad*4 + r;
          int  col = nBase + wn + j*16 + l16;
          Cout[row*N + col] = f2bf(acc[i][j][r] + bias[col]);
        }
  } else {
    // V: write transposed per head: Vt[(b*1024 + h*64 + d)*2048 + s]; 4 consecutive s -> 8B stores
    #pragma unroll
    for (int i = 0; i < 4; ++i)
      #pragma unroll
      for (int j = 0; j < 4; ++j) {
        int  col  = nBase + wn + j*16 + l16;       // = h*64+d
        long row0 = mBase + wm + i*16 + quad*4;    // token; +r consecutive
        int  bb = (int)(row0 >> 11);
        int  ss = (int)(row0 & 2047);
        float bcol = bias[col];
        float v0 = acc[i][j][0] + bcol, v1 = acc[i][j][1] + bcol;
        float v2 = acc[i][j][2] + bcol, v3 = acc[i][j][3] + bcol;
        uint2 pk;
        pk.x = (u32)f2bf(v0) | ((u32)f2bf(v1) << 16);
        pk.y = (u32)f2bf(v2) | ((u32)f2bf(v3) << 16);
        *(uint2*)&Vt[((long)(bb*16) * 64 + col) * 2048 + ss] = pk;
      }
  }
}

// ---------------- output projection GEMM (fp32 out) ----------------
__global__ __launch_bounds__(256) void gemm_out(const u16* __restrict__ A,
                                                const u16* __restrict__ Bt,
                                                const float* __restrict__ bias,
                                                float* __restrict__ Cout)
{
  constexpr int K = 1024, N = 1024, BK = 32;
  __shared__ alignas(16) u16 As[128*BK];
  __shared__ alignas(16) u16 Bs[128*BK];
  const int tid = threadIdx.x;
  const int w = tid >> 6, l = tid & 63;
  const int quad = l >> 4, l16 = l & 15;
  const int wm = (w >> 1) * 64, wn = (w & 1) * 64;
  const long mBase = (long)blockIdx.x * 128;
  const int  nBase = blockIdx.y * 128;

  f32x4 acc[4][4] = {};
  const int off0 = w*1024 + l*16;

  for (int kb = 0; kb < K/BK; ++kb) {
    __syncthreads();
    #pragma unroll
    for (int p = 0; p < 2; ++p) {
      int off = p*4096 + off0;
      int row = off >> 6;
      int cb  = off & 63;
      const u16* ga = A  + (mBase + row)*K + kb*BK + (cb >> 1);
      const u16* gb = Bt + ((long)(nBase + row))*K + kb*BK + (cb >> 1);
      gl_lds16(ga, (u16*)((char*)As + p*4096 + w*1024));
      gl_lds16(gb, (u16*)((char*)Bs + p*4096 + w*1024));
    }
    __syncthreads();
    bf16x8 af[4], bf[4];
    #pragma unroll
    for (int i = 0; i < 4; ++i) af[i] = *(const bf16x8*)&As[(wm + i*16 + l16)*BK + quad*8];
    #pragma unroll
    for (int j = 0; j < 4; ++j) bf[j] = *(const bf16x8*)&Bs[(wn + j*16 + l16)*BK + quad*8];
    #pragma unroll
    for (int i = 0; i < 4; ++i)
      #pragma unroll
      for (int j = 0; j < 4; ++j)
        acc[i][j] = __builtin_amdgcn_mfma_f32_16x16x32_bf16(af[i], bf[j], acc[i][j], 0, 0, 0);
  }

  #pragma unroll
  for (int i = 0; i < 4; ++i)
    #pragma unroll
    for (int j = 0; j < 4; ++j)
      #pragma unroll
      for (int r = 0; r < 4; ++r) {
        long row = mBase + wm + i*16 + quad*4 + r;
        int  col = nBase + wn + j*16 + l16;
        Cout[row*N + col] = acc[i][j][r] + bias[col];
      }
}

// ---------------- flash attention: zero-LDS, register-only P redistribution ----------------
// grid 2048 = qtr(16, qt=15 first) x [b(4) x h(16) x half(2)]; 256 threads = 4 waves.
// Each wave owns a 16-row q sub-tile (sw = half*4 + waveid, 0..7 within the 128-q tile).
// S^T = K*Q^T (swapped operands): lane(quad,l16) reg r holds S^T[key=j*16+quad*4+r][q=l16].
// PV B-operand needs keys ks*32+quad*8+t at the SAME l16 -> pure quad permutation.
// Pack pairs w[jp][c] = pkbf(p[2c], p[2c+1]) (keys quad*4+2c, +2c+1 of subtile jp=j&1).
// With (A,B) = (w[0][c], w[1][c]):  permlane32_swap then permlane16_swap gives
//   A' = [A@q0, A@q2, B@q0, B@q2],  B' = [A@q1, A@q3, B@q1, B@q3]  (per dest quad),
// which at dest quad d are exactly fragment words holding keys d*8+2c{,+1} (A') and
// d*8+4+2c{,+1} (B'): fragment = [A'0, A'1, B'0, B'1]. No LDS, no barriers, no waits.
// Static-shift softmax: exponent = c1*s - sl2*k (ALiBi grows toward k=0), bounded;
// no max-tracking, no rescale; distant-key underflow to 0 is exact.
__global__ __launch_bounds__(256, 8) void attn_kernel(const u16* __restrict__ Qb,
                                                      const u16* __restrict__ Kb,
                                                      const u16* __restrict__ Vt,
                                                      u16* __restrict__ Ob)
{
  const int n = blockIdx.x;
  const int qt = 15 - (n >> 7);
  const int r7 = n & 127;
  const int bh = r7 >> 1;
  const int b = bh >> 4, h = bh & 15;
  const int sw = (r7 & 1) * 4 + (threadIdx.x >> 6);   // 0..7: q sub-tile within 128-tile
  const int l = threadIdx.x & 63;
  const int quad = l >> 4, l16 = l & 15;
  const float LOG2E = 1.44269504089f;
  const float slope = exp2f(-0.5f * (float)(h + 1));
  const float c1  = 0.125f * LOG2E;
  const float sl2 = slope * LOG2E;
  const float rs1 = sl2, rs2 = 2.f*sl2, rs3 = 3.f*sl2;

  const int q0 = qt*128 + sw*16;
  const u16* Qp = Qb + ((long)(b*S_ + q0))*P_ + h*KD_;
  const u16* Kp = Kb + ((long)(b*S_))*P_ + h*KD_;
  const u16* Vp = Vt + ((long)(b*H_ + h))*KD_*S_;

  // Q fragments (MFMA B-operand for S^T = K*Q^T)
  bf16x8 qf[2];
  #pragma unroll
  for (int kk = 0; kk < 2; ++kk)
    qf[kk] = *(const bf16x8*)&Qp[(long)l16*P_ + kk*32 + quad*8];

  f32x4 o[4] = {};              // O^T accumulators: rows d (jn*16+quad*4+r), cols q=l16
  float lsum = 0.f;

  // -------- full (non-diagonal) key tiles --------
  for (int kt = 0; kt < qt; ++kt) {
    const u16* kts = Kp + (long)(kt*128 + l16)*P_;
    const float kbase = (float)(kt*128);
    #pragma unroll
    for (int ks = 0; ks < 4; ++ks) {
      u32 pw[2][2];
      #pragma unroll
      for (int jp = 0; jp < 2; ++jp) {
        const int j = 2*ks + jp;
        const u16* kp = kts + (long)(j*16)*P_;
        bf16x8 kf0 = *(const bf16x8*)(kp + quad*8);
        bf16x8 kf1 = *(const bf16x8*)(kp + 32 + quad*8);
        f32x4 t = {};
        t = __builtin_amdgcn_mfma_f32_16x16x32_bf16(kf0, qf[0], t, 0, 0, 0);
        t = __builtin_amdgcn_mfma_f32_16x16x32_bf16(kf1, qf[1], t, 0, 0, 0);
        const float bij = -sl2 * (kbase + (float)(j*16 + quad*4));
        float p0 = __builtin_amdgcn_exp2f(fmaf(t[0], c1, bij));
        float p1 = __builtin_amdgcn_exp2f(fmaf(t[1], c1, bij) - rs1);
        float p2 = __builtin_amdgcn_exp2f(fmaf(t[2], c1, bij) - rs2);
        float p3 = __builtin_amdgcn_exp2f(fmaf(t[3], c1, bij) - rs3);
        lsum += (p0 + p1) + (p2 + p3);
        pw[jp][0] = pkbf(p0, p1);
        pw[jp][1] = pkbf(p2, p3);
      }
      u32 fa0 = pw[0][0], fb0 = pw[1][0];
      u32 fa1 = pw[0][1], fb1 = pw[1][1];
      plswap(fa0, fb0);
      plswap(fa1, fb1);
      union { u32 u[4]; bf16x8 v; } fu;
      fu.u[0] = fa0; fu.u[1] = fa1; fu.u[2] = fb0; fu.u[3] = fb1;
      const bf16x8 pb = fu.v;
      #pragma unroll
      for (int jn = 0; jn < 4; ++jn) {
        bf16x8 vf = *(const bf16x8*)&Vp[(long)(jn*16 + l16)*S_ + kt*128 + ks*32 + quad*8];
        o[jn] = __builtin_amdgcn_mfma_f32_16x16x32_bf16(vf, pb, o[jn], 0, 0, 0);
      }
    }
  }

  // -------- diagonal tile (kt == qt): masked, partial j/ks ranges --------
  {
    const int kt = qt;
    const int ksmax = (sw >> 1) + 1;
    const u16* kts = Kp + (long)(kt*128 + l16)*P_;
    const int ql = sw*16 + l16;           // tile-local q row
    for (int ks = 0; ks < ksmax; ++ks) {
      u32 pw[2][2];
      #pragma unroll
      for (int jp = 0; jp < 2; ++jp) {
        const int j = 2*ks + jp;
        if (j <= sw) {
          const u16* kp = kts + (long)(j*16)*P_;
          bf16x8 kf0 = *(const bf16x8*)(kp + quad*8);
          bf16x8 kf1 = *(const bf16x8*)(kp + 32 + quad*8);
          f32x4 t = {};
          t = __builtin_amdgcn_mfma_f32_16x16x32_bf16(kf0, qf[0], t, 0, 0, 0);
          t = __builtin_amdgcn_mfma_f32_16x16x32_bf16(kf1, qf[1], t, 0, 0, 0);
          const int kl0 = j*16 + quad*4;  // tile-local key of r=0
          const float bij = -sl2 * (float)(kt*128 + kl0);
          float x0 = fmaf(t[0], c1, bij);
          float x1 = fmaf(t[1], c1, bij) - rs1;
          float x2 = fmaf(t[2], c1, bij) - rs2;
          float x3 = fmaf(t[3], c1, bij) - rs3;
          if (kl0 + 0 > ql) x0 = -1e30f;
          if (kl0 + 1 > ql) x1 = -1e30f;
          if (kl0 + 2 > ql) x2 = -1e30f;
          if (kl0 + 3 > ql) x3 = -1e30f;
          float p0 = __builtin_amdgcn_exp2f(x0);
          float p1 = __builtin_amdgcn_exp2f(x1);
          float p2 = __builtin_amdgcn_exp2f(x2);
          float p3 = __builtin_amdgcn_exp2f(x3);
          lsum += (p0 + p1) + (p2 + p3);
          pw[jp][0] = pkbf(p0, p1);
          pw[jp][1] = pkbf(p2, p3);
        } else {
          pw[jp][0] = 0u;
          pw[jp][1] = 0u;
        }
      }
      u32 fa0 = pw[0][0], fb0 = pw[1][0];
      u32 fa1 = pw[0][1], fb1 = pw[1][1];
      plswap(fa0, fb0);
      plswap(fa1, fb1);
      union { u32 u[4]; bf16x8 v; } fu;
      fu.u[0] = fa0; fu.u[1] = fa1; fu.u[2] = fb0; fu.u[3] = fb1;
      const bf16x8 pb = fu.v;
      #pragma unroll
      for (int jn = 0; jn < 4; ++jn) {
        bf16x8 vf = *(const bf16x8*)&Vp[(long)(jn*16 + l16)*S_ + kt*128 + ks*32 + quad*8];
        o[jn] = __builtin_amdgcn_mfma_f32_16x16x32_bf16(vf, pb, o[jn], 0, 0, 0);
      }
    }
  }

  // -------- epilogue: reduce lsum across quads, scale, store (8B per lane-chunk) --------
  lsum += __shfl_xor(lsum, 16, 64);
  lsum += __shfl_xor(lsum, 32, 64);
  const float inv = 1.0f / lsum;
  #pragma unroll
  for (int jn = 0; jn < 4; ++jn) {
    float v0 = o[jn][0] * inv, v1 = o[jn][1] * inv;
    float v2 = o[jn][2] * inv, v3 = o[jn][3] * inv;
    uint2 pk;
    pk.x = (u32)f2bf(v0) | ((u32)f2bf(v1) << 16);
    pk.y = (u32)f2bf(v2) | ((u32)f2bf(v3) << 16);
    *(uint2*)&Ob[((long)(b*S_ + q0 + l16))*P_ + h*KD_ + jn*16 + quad*4] = pk;
  }
}

extern "C" void kernel_launch(void* const* d_in, const int* in_sizes, int n_in,
                              void* d_out, int out_size, void* d_ws, size_t ws_size,
                              hipStream_t stream) {
  const float* q  = (const float*)d_in[0];
  const float* k  = (const float*)d_in[1];
  const float* v  = (const float*)d_in[2];
  const float* Wq = (const float*)d_in[3];
  const float* bq = (const float*)d_in[4];
  const float* Wk = (const float*)d_in[5];
  const float* bk = (const float*)d_in[6];
  const float* Wv = (const float*)d_in[7];
  const float* bv = (const float*)d_in[8];
  const float* Wo = (const float*)d_in[9];
  const float* bo = (const float*)d_in[10];

  const size_t X_ELEMS = (size_t)M_ * P_;
  const size_t W_ELEMS = (size_t)D_ * P_;
  u16* ws  = (u16*)d_ws;
  u16* Xq  = ws;
  u16* Xk  = Xq  + X_ELEMS;
  u16* Xv  = Xk  + X_ELEMS;
  u16* WqT = Xv  + X_ELEMS;
  u16* WkT = WqT + W_ELEMS;
  u16* WvT = WkT + W_ELEMS;
  u16* WoT = WvT + W_ELEMS;
  u16* Qb  = WoT + W_ELEMS;
  u16* Kb  = Qb  + X_ELEMS;
  u16* Vt  = Kb  + X_ELEMS;      // transposed V: [b][h][d][s]
  u16* Attn = Xq;                // reuse: Xq dead after projections

  cvt3_kernel<<<dim3((unsigned)(X_ELEMS/4/256), 3), 256, 0, stream>>>(q, k, v, Xq, Xk, Xv);

  transpose_cvt4<<<dim3(32, 32, 4), dim3(32, 8), 0, stream>>>(Wq, Wk, Wv, Wo,
                                                              WqT, WkT, WvT, WoT);

  gemm_qkv<<<dim3(M_/128, P_/128, 3), 256, 0, stream>>>(Xq, Xk, Xv, WqT, WkT, WvT,
                                                        bq, bk, bv, Qb, Kb, Vt);

  attn_kernel<<<dim3(2048), 256, 0, stream>>>(Qb, Kb, Vt, Attn);

  gemm_out<<<dim3(M_/128, P_/128), 256, 0, stream>>>(Attn, WoT, bo, (float*)d_out);
}

// Round 3
// 398.305 us; speedup vs baseline: 1.4206x; 1.4206x over previous
//
#include <hip/hip_runtime.h>

#define B_ 4
#define S_ 2048
#define D_ 1024
#define H_ 16
#define KD_ 64
#define P_ 1024
#define M_ (B_*S_)

typedef unsigned short u16;
typedef unsigned int u32;
typedef __attribute__((ext_vector_type(2))) unsigned u32x2;
typedef __attribute__((ext_vector_type(4))) float f32x4;
typedef __attribute__((ext_vector_type(8))) __bf16 bf16x8;

__device__ __forceinline__ u16 f2bf(float f) {
  u32 x = __float_as_uint(f);
  return (u16)((x + 0x7fffu + ((x >> 16) & 1u)) >> 16);
}

__device__ __forceinline__ void gl_lds16(const u16* g, u16* l) {
  __builtin_amdgcn_global_load_lds((__attribute__((address_space(1))) void*)g,
                                   (__attribute__((address_space(3))) void*)l, 16, 0, 0);
}

// pack bf16(b)<<16 | bf16(a), round-to-nearest (+0x8000 then take hi16 via v_perm)
__device__ __forceinline__ u32 pkbf(float a, float b) {
  return __builtin_amdgcn_perm(__float_as_uint(b) + 0x8000u,
                               __float_as_uint(a) + 0x8000u, 0x07060302u);
}

// Quad redistribution for P -> PV B-operand (proven in round 2).
// After this: a = [a@q0, a@q2, b@q0, b@q2], b = [a@q1, a@q3, b@q1, b@q3]
// (x@qN = value of x at source quad N, same l16).
#if __has_builtin(__builtin_amdgcn_permlane32_swap) && __has_builtin(__builtin_amdgcn_permlane16_swap)
__device__ __forceinline__ void plswap(u32& a, u32& b) {
  u32x2 r32 = __builtin_amdgcn_permlane32_swap(a, b, false, false);
  u32x2 r16 = __builtin_amdgcn_permlane16_swap(r32[0], r32[1], false, false);
  a = r16[0]; b = r16[1];
}
#else
__device__ __forceinline__ void plswap(u32& a, u32& b) {
  const int l = threadIdx.x & 63;
  const int quad = l >> 4, l16 = l & 15;
  int i0 = (((quad & 1) * 32) + l16) * 4;
  int i1 = i0 + 64;
  int a_lo = __builtin_amdgcn_ds_bpermute(i0, (int)a);
  int b_lo = __builtin_amdgcn_ds_bpermute(i0, (int)b);
  int a_hi = __builtin_amdgcn_ds_bpermute(i1, (int)a);
  int b_hi = __builtin_amdgcn_ds_bpermute(i1, (int)b);
  u32 na = (quad < 2) ? (u32)a_lo : (u32)b_lo;
  u32 nb = (quad < 2) ? (u32)a_hi : (u32)b_hi;
  a = na; b = nb;
}
#endif

// ---------------- fp32 -> bf16 convert, 3 tensors in one launch ----------------
__global__ void cvt3_kernel(const float* __restrict__ q, const float* __restrict__ k,
                            const float* __restrict__ v,
                            u16* __restrict__ Xq, u16* __restrict__ Xk, u16* __restrict__ Xv) {
  const int z = blockIdx.y;
  const float* in = z == 0 ? q : z == 1 ? k : v;
  u16* out = z == 0 ? Xq : z == 1 ? Xk : Xv;
  int i = blockIdx.x * 256 + threadIdx.x;
  float4 vv = ((const float4*)in)[i];
  ((u32*)out)[i*2+0] = (u32)f2bf(vv.x) | ((u32)f2bf(vv.y) << 16);
  ((u32*)out)[i*2+1] = (u32)f2bf(vv.z) | ((u32)f2bf(vv.w) << 16);
}

// ---------------- transpose 1024x1024 fp32 -> bf16 [C][R], 4 weights ----------------
__global__ void transpose_cvt4(const float* __restrict__ Wq, const float* __restrict__ Wk,
                               const float* __restrict__ Wv, const float* __restrict__ Wo,
                               u16* __restrict__ WqT, u16* __restrict__ WkT,
                               u16* __restrict__ WvT, u16* __restrict__ WoT) {
  const int z = blockIdx.z;
  const float* in = z == 0 ? Wq : z == 1 ? Wk : z == 2 ? Wv : Wo;
  u16* out = z == 0 ? WqT : z == 1 ? WkT : z == 2 ? WvT : WoT;
  __shared__ float tile[32][33];
  int bx = blockIdx.x * 32, by = blockIdx.y * 32;
  int tx = threadIdx.x, ty = threadIdx.y; // block (32,8)
  #pragma unroll
  for (int kk = 0; kk < 4; ++kk)
    tile[ty + kk*8][tx] = in[(by + ty + kk*8) * 1024 + bx + tx];
  __syncthreads();
  #pragma unroll
  for (int kk = 0; kk < 4; ++kk)
    out[(bx + ty + kk*8) * 1024 + by + tx] = f2bf(tile[tx][ty + kk*8]);
}

// ---------------- QKV projection GEMM (batched, z selects), m97 pattern ----------------
// z=0: Q -> Qb [row][P]; z=1: K -> Kb [row][P]; z=2: V -> Vt [b][h][d][s] (transposed!)
__global__ __launch_bounds__(256) void gemm_qkv(
    const u16* __restrict__ Xq, const u16* __restrict__ Xk, const u16* __restrict__ Xv,
    const u16* __restrict__ WqT, const u16* __restrict__ WkT, const u16* __restrict__ WvT,
    const float* __restrict__ bq, const float* __restrict__ bk, const float* __restrict__ bv,
    u16* __restrict__ Qb, u16* __restrict__ Kb, u16* __restrict__ Vt)
{
  constexpr int K = 1024, N = 1024, BK = 32;
  const int z = blockIdx.z;
  const u16* A  = z == 0 ? Xq  : z == 1 ? Xk  : Xv;
  const u16* Bt = z == 0 ? WqT : z == 1 ? WkT : WvT;
  const float* bias = z == 0 ? bq : z == 1 ? bk : bv;

  __shared__ alignas(16) u16 As[128*BK];
  __shared__ alignas(16) u16 Bs[128*BK];
  const int tid = threadIdx.x;
  const int w = tid >> 6, l = tid & 63;
  const int quad = l >> 4, l16 = l & 15;
  const int wm = (w >> 1) * 64, wn = (w & 1) * 64;
  const long mBase = (long)blockIdx.x * 128;
  const int  nBase = blockIdx.y * 128;

  f32x4 acc[4][4] = {};
  const int off0 = w*1024 + l*16;

  for (int kb = 0; kb < K/BK; ++kb) {
    __syncthreads();
    #pragma unroll
    for (int p = 0; p < 2; ++p) {
      int off = p*4096 + off0;
      int row = off >> 6;
      int cb  = off & 63;
      const u16* ga = A  + (mBase + row)*K + kb*BK + (cb >> 1);
      const u16* gb = Bt + ((long)(nBase + row))*K + kb*BK + (cb >> 1);
      gl_lds16(ga, (u16*)((char*)As + p*4096 + w*1024));
      gl_lds16(gb, (u16*)((char*)Bs + p*4096 + w*1024));
    }
    __syncthreads();
    bf16x8 af[4], bf[4];
    #pragma unroll
    for (int i = 0; i < 4; ++i) af[i] = *(const bf16x8*)&As[(wm + i*16 + l16)*BK + quad*8];
    #pragma unroll
    for (int j = 0; j < 4; ++j) bf[j] = *(const bf16x8*)&Bs[(wn + j*16 + l16)*BK + quad*8];
    #pragma unroll
    for (int i = 0; i < 4; ++i)
      #pragma unroll
      for (int j = 0; j < 4; ++j)
        acc[i][j] = __builtin_amdgcn_mfma_f32_16x16x32_bf16(af[i], bf[j], acc[i][j], 0, 0, 0);
  }

  if (z < 2) {
    u16* Cout = z == 0 ? Qb : Kb;
    #pragma unroll
    for (int i = 0; i < 4; ++i)
      #pragma unroll
      for (int j = 0; j < 4; ++j)
        #pragma unroll
        for (int r = 0; r < 4; ++r) {
          long row = mBase + wm + i*16 + quad*4 + r;
          int  col = nBase + wn + j*16 + l16;
          Cout[row*N + col] = f2bf(acc[i][j][r] + bias[col]);
        }
  } else {
    // V: write transposed per head: Vt[(b*1024 + h*64 + d)*2048 + s]; 4 consecutive s -> 8B stores
    #pragma unroll
    for (int i = 0; i < 4; ++i)
      #pragma unroll
      for (int j = 0; j < 4; ++j) {
        int  col  = nBase + wn + j*16 + l16;       // = h*64+d
        long row0 = mBase + wm + i*16 + quad*4;    // token; +r consecutive
        int  bb = (int)(row0 >> 11);
        int  ss = (int)(row0 & 2047);
        float bcol = bias[col];
        float v0 = acc[i][j][0] + bcol, v1 = acc[i][j][1] + bcol;
        float v2 = acc[i][j][2] + bcol, v3 = acc[i][j][3] + bcol;
        uint2 pk;
        pk.x = (u32)f2bf(v0) | ((u32)f2bf(v1) << 16);
        pk.y = (u32)f2bf(v2) | ((u32)f2bf(v3) << 16);
        *(uint2*)&Vt[((long)(bb*16) * 64 + col) * 2048 + ss] = pk;
      }
  }
}

// ---------------- output projection GEMM (fp32 out) ----------------
__global__ __launch_bounds__(256) void gemm_out(const u16* __restrict__ A,
                                                const u16* __restrict__ Bt,
                                                const float* __restrict__ bias,
                                                float* __restrict__ Cout)
{
  constexpr int K = 1024, N = 1024, BK = 32;
  __shared__ alignas(16) u16 As[128*BK];
  __shared__ alignas(16) u16 Bs[128*BK];
  const int tid = threadIdx.x;
  const int w = tid >> 6, l = tid & 63;
  const int quad = l >> 4, l16 = l & 15;
  const int wm = (w >> 1) * 64, wn = (w & 1) * 64;
  const long mBase = (long)blockIdx.x * 128;
  const int  nBase = blockIdx.y * 128;

  f32x4 acc[4][4] = {};
  const int off0 = w*1024 + l*16;

  for (int kb = 0; kb < K/BK; ++kb) {
    __syncthreads();
    #pragma unroll
    for (int p = 0; p < 2; ++p) {
      int off = p*4096 + off0;
      int row = off >> 6;
      int cb  = off & 63;
      const u16* ga = A  + (mBase + row)*K + kb*BK + (cb >> 1);
      const u16* gb = Bt + ((long)(nBase + row))*K + kb*BK + (cb >> 1);
      gl_lds16(ga, (u16*)((char*)As + p*4096 + w*1024));
      gl_lds16(gb, (u16*)((char*)Bs + p*4096 + w*1024));
    }
    __syncthreads();
    bf16x8 af[4], bf[4];
    #pragma unroll
    for (int i = 0; i < 4; ++i) af[i] = *(const bf16x8*)&As[(wm + i*16 + l16)*BK + quad*8];
    #pragma unroll
    for (int j = 0; j < 4; ++j) bf[j] = *(const bf16x8*)&Bs[(wn + j*16 + l16)*BK + quad*8];
    #pragma unroll
    for (int i = 0; i < 4; ++i)
      #pragma unroll
      for (int j = 0; j < 4; ++j)
        acc[i][j] = __builtin_amdgcn_mfma_f32_16x16x32_bf16(af[i], bf[j], acc[i][j], 0, 0, 0);
  }

  #pragma unroll
  for (int i = 0; i < 4; ++i)
    #pragma unroll
    for (int j = 0; j < 4; ++j)
      #pragma unroll
      for (int r = 0; r < 4; ++r) {
        long row = mBase + wm + i*16 + quad*4 + r;
        int  col = nBase + wn + j*16 + l16;
        Cout[row*N + col] = acc[i][j][r] + bias[col];
      }
}

// ---------------- flash attention: round-0 geometry + register-only P (no LDS) ----------------
// grid 4096 = qtr(16, qt=15 first) x [b(4) x h(16) x w(4)]; 64 threads = 1 wave, 32 q-rows/wave.
// S^T = K*Q^T (swapped operands): lane(quad,l16) reg r holds S^T[key=j*16+quad*4+r][q=l16].
// PV B-operand needs keys ks*32+quad*8+t at the SAME l16 -> pure quad permutation:
//   pack pairs pw[i][jp][c] = pkbf(p[2c], p[2c+1]); plswap(pw[i][0][c], pw[i][1][c])
//   (permlane32_swap then permlane16_swap) yields fragment words [A'0,A'1,B'0,B'1]
//   holding keys quad*8+{2c,2c+1} and quad*8+4+{2c,2c+1}. No LDS, no barriers, no lgkm waits.
// Static-shift softmax: exponent = c1*s - sl2*k (ALiBi grows toward k=0), bounded;
// no max-tracking, no rescale; distant-key underflow to 0 is exact.
__global__ __launch_bounds__(64, 3) void attn_kernel(const u16* __restrict__ Qb,
                                                     const u16* __restrict__ Kb,
                                                     const u16* __restrict__ Vt,
                                                     u16* __restrict__ Ob)
{
  const int n = blockIdx.x;
  const int qt = 15 - (n >> 8);
  const int r8 = n & 255;
  const int b = r8 >> 6, h = (r8 >> 2) & 15, w = r8 & 3;
  const int l = threadIdx.x;
  const int quad = l >> 4, l16 = l & 15;
  const float LOG2E = 1.44269504089f;
  const float slope = exp2f(-0.5f * (float)(h + 1));
  const float c1  = 0.125f * LOG2E;
  const float sl2 = slope * LOG2E;
  const float rs1 = sl2, rs2 = 2.f*sl2, rs3 = 3.f*sl2;

  const int q0 = qt*128 + w*32;
  const u16* Qp = Qb + ((long)(b*S_ + q0))*P_ + h*KD_;
  const u16* Kp = Kb + ((long)(b*S_))*P_ + h*KD_;
  const u16* Vp = Vt + ((long)(b*H_ + h))*KD_*S_;

  // Q fragments (MFMA B-operand for S^T = K*Q^T)
  bf16x8 qf[2][2];
  #pragma unroll
  for (int i = 0; i < 2; ++i)
    #pragma unroll
    for (int kk = 0; kk < 2; ++kk)
      qf[i][kk] = *(const bf16x8*)&Qp[(long)(i*16 + l16)*P_ + kk*32 + quad*8];

  f32x4 o[2][4] = {};           // O^T accumulators: rows d (jn*16+quad*4+r), cols q=l16
  float lsum[2] = {0.f, 0.f};

  // -------- full (non-diagonal) key tiles --------
  for (int kt = 0; kt < qt; ++kt) {
    const u16* kts = Kp + (long)(kt*128 + l16)*P_;
    const float kbase = (float)(kt*128);
    #pragma unroll
    for (int ks = 0; ks < 4; ++ks) {
      u32 pw[2][2][2];          // [i][jp][c]
      #pragma unroll
      for (int jp = 0; jp < 2; ++jp) {
        const int j = 2*ks + jp;
        const u16* kp = kts + (long)(j*16)*P_;
        bf16x8 kf0 = *(const bf16x8*)(kp + quad*8);
        bf16x8 kf1 = *(const bf16x8*)(kp + 32 + quad*8);
        const float bij = -sl2 * (kbase + (float)(j*16 + quad*4));
        #pragma unroll
        for (int i = 0; i < 2; ++i) {
          f32x4 t = {};
          t = __builtin_amdgcn_mfma_f32_16x16x32_bf16(kf0, qf[i][0], t, 0, 0, 0);
          t = __builtin_amdgcn_mfma_f32_16x16x32_bf16(kf1, qf[i][1], t, 0, 0, 0);
          float p0 = __builtin_amdgcn_exp2f(fmaf(t[0], c1, bij));
          float p1 = __builtin_amdgcn_exp2f(fmaf(t[1], c1, bij) - rs1);
          float p2 = __builtin_amdgcn_exp2f(fmaf(t[2], c1, bij) - rs2);
          float p3 = __builtin_amdgcn_exp2f(fmaf(t[3], c1, bij) - rs3);
          lsum[i] += (p0 + p1) + (p2 + p3);
          pw[i][jp][0] = pkbf(p0, p1);
          pw[i][jp][1] = pkbf(p2, p3);
        }
      }
      bf16x8 pb[2];
      #pragma unroll
      for (int i = 0; i < 2; ++i) {
        u32 fa0 = pw[i][0][0], fb0 = pw[i][1][0];
        u32 fa1 = pw[i][0][1], fb1 = pw[i][1][1];
        plswap(fa0, fb0);
        plswap(fa1, fb1);
        union { u32 u[4]; bf16x8 v; } fu;
        fu.u[0] = fa0; fu.u[1] = fa1; fu.u[2] = fb0; fu.u[3] = fb1;
        pb[i] = fu.v;
      }
      #pragma unroll
      for (int jn = 0; jn < 4; ++jn) {
        bf16x8 vf = *(const bf16x8*)&Vp[(long)(jn*16 + l16)*S_ + kt*128 + ks*32 + quad*8];
        o[0][jn] = __builtin_amdgcn_mfma_f32_16x16x32_bf16(vf, pb[0], o[0][jn], 0, 0, 0);
        o[1][jn] = __builtin_amdgcn_mfma_f32_16x16x32_bf16(vf, pb[1], o[1][jn], 0, 0, 0);
      }
    }
  }

  // -------- diagonal tile (kt == qt): masked, partial ks range --------
  {
    const int kt = qt;
    const int ksmax = w + 1;    // keys up to tile-local 32*w+31 = exactly ks pairs 0..w
    const u16* kts = Kp + (long)(kt*128 + l16)*P_;
    for (int ks = 0; ks < ksmax; ++ks) {
      u32 pw[2][2][2];
      #pragma unroll
      for (int jp = 0; jp < 2; ++jp) {
        const int j = 2*ks + jp;
        const u16* kp = kts + (long)(j*16)*P_;
        bf16x8 kf0 = *(const bf16x8*)(kp + quad*8);
        bf16x8 kf1 = *(const bf16x8*)(kp + 32 + quad*8);
        const int kl0 = j*16 + quad*4;  // tile-local key of r=0
        const float bij = -sl2 * (float)(kt*128 + kl0);
        #pragma unroll
        for (int i = 0; i < 2; ++i) {
          const int ql = w*32 + i*16 + l16;   // tile-local q row
          f32x4 t = {};
          t = __builtin_amdgcn_mfma_f32_16x16x32_bf16(kf0, qf[i][0], t, 0, 0, 0);
          t = __builtin_amdgcn_mfma_f32_16x16x32_bf16(kf1, qf[i][1], t, 0, 0, 0);
          float x0 = fmaf(t[0], c1, bij);
          float x1 = fmaf(t[1], c1, bij) - rs1;
          float x2 = fmaf(t[2], c1, bij) - rs2;
          float x3 = fmaf(t[3], c1, bij) - rs3;
          if (kl0 + 0 > ql) x0 = -1e30f;
          if (kl0 + 1 > ql) x1 = -1e30f;
          if (kl0 + 2 > ql) x2 = -1e30f;
          if (kl0 + 3 > ql) x3 = -1e30f;
          float p0 = __builtin_amdgcn_exp2f(x0);
          float p1 = __builtin_amdgcn_exp2f(x1);
          float p2 = __builtin_amdgcn_exp2f(x2);
          float p3 = __builtin_amdgcn_exp2f(x3);
          lsum[i] += (p0 + p1) + (p2 + p3);
          pw[i][jp][0] = pkbf(p0, p1);
          pw[i][jp][1] = pkbf(p2, p3);
        }
      }
      bf16x8 pb[2];
      #pragma unroll
      for (int i = 0; i < 2; ++i) {
        u32 fa0 = pw[i][0][0], fb0 = pw[i][1][0];
        u32 fa1 = pw[i][0][1], fb1 = pw[i][1][1];
        plswap(fa0, fb0);
        plswap(fa1, fb1);
        union { u32 u[4]; bf16x8 v; } fu;
        fu.u[0] = fa0; fu.u[1] = fa1; fu.u[2] = fb0; fu.u[3] = fb1;
        pb[i] = fu.v;
      }
      #pragma unroll
      for (int jn = 0; jn < 4; ++jn) {
        bf16x8 vf = *(const bf16x8*)&Vp[(long)(jn*16 + l16)*S_ + kt*128 + ks*32 + quad*8];
        o[0][jn] = __builtin_amdgcn_mfma_f32_16x16x32_bf16(vf, pb[0], o[0][jn], 0, 0, 0);
        o[1][jn] = __builtin_amdgcn_mfma_f32_16x16x32_bf16(vf, pb[1], o[1][jn], 0, 0, 0);
      }
    }
  }

  // -------- epilogue: reduce lsum across quads, scale, store (8B per lane-chunk) --------
  #pragma unroll
  for (int i = 0; i < 2; ++i) {
    lsum[i] += __shfl_xor(lsum[i], 16, 64);
    lsum[i] += __shfl_xor(lsum[i], 32, 64);
    const float inv = 1.0f / lsum[i];
    #pragma unroll
    for (int jn = 0; jn < 4; ++jn) {
      float v0 = o[i][jn][0] * inv, v1 = o[i][jn][1] * inv;
      float v2 = o[i][jn][2] * inv, v3 = o[i][jn][3] * inv;
      uint2 pk;
      pk.x = (u32)f2bf(v0) | ((u32)f2bf(v1) << 16);
      pk.y = (u32)f2bf(v2) | ((u32)f2bf(v3) << 16);
      *(uint2*)&Ob[((long)(b*S_ + q0 + i*16 + l16))*P_ + h*KD_ + jn*16 + quad*4] = pk;
    }
  }
}

extern "C" void kernel_launch(void* const* d_in, const int* in_sizes, int n_in,
                              void* d_out, int out_size, void* d_ws, size_t ws_size,
                              hipStream_t stream) {
  const float* q  = (const float*)d_in[0];
  const float* k  = (const float*)d_in[1];
  const float* v  = (const float*)d_in[2];
  const float* Wq = (const float*)d_in[3];
  const float* bq = (const float*)d_in[4];
  const float* Wk = (const float*)d_in[5];
  const float* bk = (const float*)d_in[6];
  const float* Wv = (const float*)d_in[7];
  const float* bv = (const float*)d_in[8];
  const float* Wo = (const float*)d_in[9];
  const float* bo = (const float*)d_in[10];

  const size_t X_ELEMS = (size_t)M_ * P_;
  const size_t W_ELEMS = (size_t)D_ * P_;
  u16* ws  = (u16*)d_ws;
  u16* Xq  = ws;
  u16* Xk  = Xq  + X_ELEMS;
  u16* Xv  = Xk  + X_ELEMS;
  u16* WqT = Xv  + X_ELEMS;
  u16* WkT = WqT + W_ELEMS;
  u16* WvT = WkT + W_ELEMS;
  u16* WoT = WvT + W_ELEMS;
  u16* Qb  = WoT + W_ELEMS;
  u16* Kb  = Qb  + X_ELEMS;
  u16* Vt  = Kb  + X_ELEMS;      // transposed V: [b][h][d][s]
  u16* Attn = Xq;                // reuse: Xq dead after projections

  cvt3_kernel<<<dim3((unsigned)(X_ELEMS/4/256), 3), 256, 0, stream>>>(q, k, v, Xq, Xk, Xv);

  transpose_cvt4<<<dim3(32, 32, 4), dim3(32, 8), 0, stream>>>(Wq, Wk, Wv, Wo,
                                                              WqT, WkT, WvT, WoT);

  gemm_qkv<<<dim3(M_/128, P_/128, 3), 256, 0, stream>>>(Xq, Xk, Xv, WqT, WkT, WvT,
                                                        bq, bk, bv, Qb, Kb, Vt);

  attn_kernel<<<dim3(4096), 64, 0, stream>>>(Qb, Kb, Vt, Attn);

  gemm_out<<<dim3(M_/128, P_/128), 256, 0, stream>>>(Attn, WoT, bo, (float*)d_out);
}